// Round 13
// baseline (137.373 us; speedup 1.0000x reference)
//
#include <hip/hip_runtime.h>
#include <math.h>

#define DD 4096
#define EE 64
#define TAU 1e-4f
#define NEG_SENTINEL -1.0e30f
#define MAXFIX 4096

typedef __attribute__((ext_vector_type(8))) short short8v;
typedef __attribute__((ext_vector_type(4))) float f32x4;

union BF8 { uint4 u; short8v s; };

__device__ __forceinline__ unsigned asu(float f) {
  union { float f; unsigned u; } v; v.f = f; return v.u;
}
__device__ __forceinline__ float asf(unsigned u) {
  union { unsigned u; float f; } v; v.u = u; return v.f;
}
__device__ __forceinline__ unsigned rne_hi(float x) {  // bf16 bits<<16
  unsigned u = asu(x);
  return (u + 0x7fffu + ((u >> 16) & 1u)) & 0xffff0000u;
}
// Split 8 f32 into hi/lo bf16 (RNE both): x = hi + lo + O(2^-17 |x|).
__device__ __forceinline__ void split8(const float x[8], uint4& hi, uint4& lo) {
  unsigned h[8], l[8];
#pragma unroll
  for (int j = 0; j < 8; j++) {
    h[j] = rne_hi(x[j]);
    l[j] = rne_hi(x[j] - asf(h[j]));
  }
  hi = make_uint4((h[0] >> 16) | h[1], (h[2] >> 16) | h[3],
                  (h[4] >> 16) | h[5], (h[6] >> 16) | h[7]);
  lo = make_uint4((l[0] >> 16) | l[1], (l[2] >> 16) | l[3],
                  (l[4] >> 16) | l[5], (l[6] >> 16) | l[7]);
}
// global -> LDS direct copy, 16B/lane; LDS dest wave-uniform (HW adds l*16).
__device__ __forceinline__ void gload16(const void* g, void* l) {
  __builtin_amdgcn_global_load_lds(
      (const __attribute__((address_space(1))) uint32_t*)(uintptr_t)g,
      (__attribute__((address_space(3))) uint32_t*)(uint32_t)(uintptr_t)l, 16,
      0, 0);
}

// ---------------------------------------------------------------------------
// Kernel 0: pre-split gate_w into bf16 hi/lo in the gemm's exact STAGED
// layout (unchanged from R12): bglob[slice][step(32k)][hi|lo][e][slot16B],
// read-side swizzle baked in: octet o of expert e -> slot o ^ ((e>>1)&3).
// ---------------------------------------------------------------------------
__global__ __launch_bounds__(256) void presplit_b(const float* __restrict__ gw,
                                                  char* __restrict__ bglob) {
  const int t = blockIdx.x * 256 + threadIdx.x;  // 64 e x 512 octets
  const int e = t >> 9;
  const int o = t & 511;
  const int slice = o >> 7;
  const int ow = o & 127;
  const int step = ow >> 2;
  const int oslot = ow & 3;
  const float* src = gw + e * DD + o * 8;
  float4 v0 = *(const float4*)src;
  float4 v1 = *(const float4*)(src + 4);
  float x[8] = {v0.x, v0.y, v0.z, v0.w, v1.x, v1.y, v1.z, v1.w};
  uint4 hi, lo;
  split8(x, hi, lo);
  char* dst = bglob + (size_t)slice * 262144 + step * 8192 + e * 64 +
              ((oslot ^ ((e >> 1) & 3)) << 4);
  *(uint4*)dst = hi;
  *(uint4*)(dst + 4096) = lo;
}

// ---------------------------------------------------------------------------
// Kernel 1 (R13): R12 tile + DEPTH-4 COUNTED-VMCNT RING (T4).
// Per region t: issue stage(t+2) -> s_waitcnt vmcnt(8) (own stage(t) done;
// t+1/t+2 in flight) -> s_barrier (all waves' stage(t) verified) ->
// compute(t). NO vmcnt(0) in-loop. Ring: 4 x {A 8KB f32, B 8KB bf16 hi/lo}
// = 64KB -> 2 blocks/CU. Tail: vmcnt(4) at t=30, vmcnt(0) at t=31.
// Race audit (skew-0 between barriers): window t = compute(t) || issue
// stage(t+3): reads t%4, writes (t+3)%4 distinct; late-landing stage(t+2)
// writes (t+2)%4 vs reads t,(t+1) distinct.
// ---------------------------------------------------------------------------
__global__ __launch_bounds__(256, 2) void gemm_mfma(
    const float* __restrict__ hidden, const char* __restrict__ bglob,
    float* __restrict__ part, int nrows) {
  __shared__ __align__(16) char smem[65536];  // 4 bufs x [A 8K | B 8K]

  const int lane = threadIdx.x & 63;
  const int wv = threadIdx.x >> 6;
  const int fr = lane & 15;
  const int fg = lane >> 4;  // 0..3
  const int m0 = blockIdx.x * 64;
  const int slice = blockIdx.y;  // ksplit = 4, kslice = 1024
  const int k0 = slice * 1024;

  // A sources (R12-proven): wave wv stages rows 16wv..+15; instr i covers
  // rows 8i..8i+7. lane l -> rloc = 8i+(l>>3), source slot (l&7)^(rloc&7).
  const float* srcA[2];
#pragma unroll
  for (int i = 0; i < 2; i++) {
    const int rloc = 8 * i + (lane >> 3);
    const int s = (lane & 7) ^ (rloc & 7);
    srcA[i] = hidden + (size_t)(m0 + 16 * wv + rloc) * DD + k0 + s * 4;
  }
  const char* srcB = bglob + (size_t)slice * 262144 + wv * 2048 + lane * 16;

  auto stage = [&](int t) {
    const int buf = t & 3;
    char* ad = smem + buf * 16384 + wv * 2048;
    char* bd = smem + buf * 16384 + 8192 + wv * 2048;
#pragma unroll
    for (int i = 0; i < 2; i++) {
      gload16(srcA[i] + t * 32, ad + i * 1024);
      gload16(srcB + t * 8192 + i * 1024, bd + i * 1024);
    }
  };

  f32x4 zero4 = {0.f, 0.f, 0.f, 0.f};
  f32x4 acc[4];
#pragma unroll
  for (int nt = 0; nt < 4; nt++) acc[nt] = zero4;

  const int abase = wv * 2048 + fr * 128;
  const int bslot = (fg ^ ((fr >> 1) & 3)) << 4;

  // prologue: fill pipeline 2 deep
  stage(0);
  stage(1);

  for (int t = 0; t < 32; t++) {
    if (t < 30) {
      stage(t + 2);
      asm volatile("s_waitcnt vmcnt(8)" ::: "memory");
    } else if (t == 30) {
      asm volatile("s_waitcnt vmcnt(4)" ::: "memory");
    } else {
      asm volatile("s_waitcnt vmcnt(0)" ::: "memory");
    }
    __builtin_amdgcn_s_barrier();
    asm volatile("" ::: "memory");

    const char* Ab = smem + (t & 3) * 16384;
    const char* Bb = Ab + 8192;
    // A frag: 8 consecutive k-floats via 2 swizzled b128 reads
    float4 a0 = *(const float4*)(Ab + abase + (((2 * fg + 0) ^ (fr & 7)) << 4));
    float4 a1 = *(const float4*)(Ab + abase + (((2 * fg + 1) ^ (fr & 7)) << 4));
    float xa[8] = {a0.x, a0.y, a0.z, a0.w, a1.x, a1.y, a1.z, a1.w};
    BF8 ah, al;
    split8(xa, ah.u, al.u);
    BF8 bh[4], bl[4];
#pragma unroll
    for (int nt = 0; nt < 4; nt++) {
      const int boff = (nt * 16 + fr) * 64 + bslot;
      bh[nt].u = *(const uint4*)(Bb + boff);
      bl[nt].u = *(const uint4*)(Bb + 4096 + boff);
    }
    // 12 MFMAs, pass-outer (per-acc order hh->hl->lh, deterministic)
#pragma unroll
    for (int nt = 0; nt < 4; nt++)
      acc[nt] = __builtin_amdgcn_mfma_f32_16x16x32_bf16(ah.s, bh[nt].s,
                                                        acc[nt], 0, 0, 0);
#pragma unroll
    for (int nt = 0; nt < 4; nt++)
      acc[nt] = __builtin_amdgcn_mfma_f32_16x16x32_bf16(ah.s, bl[nt].s,
                                                        acc[nt], 0, 0, 0);
#pragma unroll
    for (int nt = 0; nt < 4; nt++)
      acc[nt] = __builtin_amdgcn_mfma_f32_16x16x32_bf16(al.s, bh[nt].s,
                                                        acc[nt], 0, 0, 0);
  }

  // partial logits part[slice][row][e]; C/D row=fg*4+j, col=fr
  float* dst = part + (size_t)slice * nrows * EE;
#pragma unroll
  for (int j = 0; j < 4; j++) {
    const int r = m0 + 16 * wv + fg * 4 + j;
#pragma unroll
    for (int nt = 0; nt < 4; nt++)
      dst[(size_t)r * EE + nt * 16 + fr] = acc[nt][j];
  }
}

// ---------------------------------------------------------------------------
// Kernel 2: reduce partials, sqrt(softplus), top-8 (lax.top_k tie-break),
// renormalize, scatter. Flags rows with margin < TAU for exact recompute.
// ---------------------------------------------------------------------------
__global__ __launch_bounds__(256) void topk_kernel(
    const float* __restrict__ part, const float* __restrict__ bias,
    float* __restrict__ out, int nrows, int ksplit, int* __restrict__ counter,
    int* __restrict__ list) {
  const int lane = threadIdx.x & 63;
  const int row = blockIdx.x * 4 + (threadIdx.x >> 6);

  float logit = 0.0f;
  for (int s = 0; s < ksplit; s++)
    logit += part[(size_t)s * nrows * EE + (size_t)row * EE + lane];

  float sp = (logit > 0.0f) ? (logit + log1pf(expf(-logit)))
                            : log1pf(expf(logit));
  float score = sqrtf(sp);
  float sel = score + bias[lane];

  float denom = 0.0f, v8 = 0.0f;
  bool chosen = false;
#pragma unroll
  for (int t = 0; t < 8; t++) {
    float v = sel;
    int idx = lane;
#pragma unroll
    for (int m = 1; m < 64; m <<= 1) {
      float ov = __shfl_xor(v, m, 64);
      int oi = __shfl_xor(idx, m, 64);
      if (ov > v || (ov == v && oi < idx)) { v = ov; idx = oi; }
    }
    float wscore = __shfl(score, idx, 64);
    denom += wscore;
    v8 = v;
    if (lane == idx) { chosen = true; sel = NEG_SENTINEL; }
  }
  float v9 = sel;
#pragma unroll
  for (int m = 1; m < 64; m <<= 1) v9 = fmaxf(v9, __shfl_xor(v9, m, 64));
  if (lane == 0 && (v8 - v9) < TAU) {
    int ix = atomicAdd(counter, 1);
    if (ix < MAXFIX) list[ix] = row;
  }

  denom = fmaxf(denom, 1e-12f);
  out[(size_t)row * EE + lane] = chosen ? (score / denom) : 0.0f;
  out[(size_t)nrows * EE + (size_t)row * EE + lane] = chosen ? 1.0f : 0.0f;
}

// ---------------------------------------------------------------------------
// Kernel 3a: exact-f32 partial dots for flagged rows, k-split 16 ways.
// ---------------------------------------------------------------------------
__global__ __launch_bounds__(256) void fixup_partial(
    const float* __restrict__ hidden, const float* __restrict__ gate_w,
    const int* __restrict__ counter, const int* __restrict__ list,
    float* __restrict__ part2) {
  __shared__ float red[EE][4];
  int cnt = *counter;
  if (cnt > MAXFIX) cnt = MAXFIX;
  const int total = cnt * 16;
  const int e = threadIdx.x & 63;
  const int q = threadIdx.x >> 6;
  for (int w = blockIdx.x; w < total; w += gridDim.x) {
    const int i = w >> 4;
    const int c = w & 15;
    const int row = list[i];
    const int kb = c * 256 + q * 64;
    const float* hp = hidden + (size_t)row * DD + kb;
    const float* wp = gate_w + (size_t)e * DD + kb;
    float s = 0.f;
#pragma unroll
    for (int k = 0; k < 64; k += 4) {
      float4 aa = *(const float4*)(hp + k);
      float4 bb = *(const float4*)(wp + k);
      s = fmaf(aa.w, bb.w, fmaf(aa.z, bb.z, fmaf(aa.y, bb.y, fmaf(aa.x, bb.x, s))));
    }
    red[e][q] = s;
    __syncthreads();
    if (threadIdx.x < EE)
      part2[(size_t)i * 1024 + threadIdx.x * 16 + c] =
          (red[threadIdx.x][0] + red[threadIdx.x][1]) +
          (red[threadIdx.x][2] + red[threadIdx.x][3]);
    __syncthreads();
  }
}

// ---------------------------------------------------------------------------
// Kernel 3b: sum the 16 chunks in fixed order, redo top-8 exactly, rewrite.
// ---------------------------------------------------------------------------
__global__ __launch_bounds__(256) void fixup_apply(
    const float* __restrict__ part2, const float* __restrict__ bias,
    const int* __restrict__ counter, const int* __restrict__ list,
    float* __restrict__ out, int nrows) {
  int cnt = *counter;
  if (cnt > MAXFIX) cnt = MAXFIX;
  const int lane = threadIdx.x & 63;
  const int wv = threadIdx.x >> 6;
  for (int i0 = blockIdx.x * 4; i0 < cnt; i0 += gridDim.x * 4) {
    const int i = i0 + wv;
    if (i >= cnt) continue;
    const int row = list[i];
    const float* pp = part2 + (size_t)i * 1024 + lane * 16;
    float logit = 0.f;
#pragma unroll
    for (int c = 0; c < 16; c++) logit += pp[c];
    float sp = (logit > 0.0f) ? (logit + log1pf(expf(-logit)))
                              : log1pf(expf(logit));
    float score = sqrtf(sp);
    float sel = score + bias[lane];
    float denom = 0.0f;
    bool chosen = false;
#pragma unroll
    for (int k = 0; k < 8; k++) {
      float v = sel;
      int idx = lane;
#pragma unroll
      for (int m = 1; m < 64; m <<= 1) {
        float ov = __shfl_xor(v, m, 64);
        int oi = __shfl_xor(idx, m, 64);
        if (ov > v || (ov == v && oi < idx)) { v = ov; idx = oi; }
      }
      float wscore = __shfl(score, idx, 64);
      denom += wscore;
      if (lane == idx) { chosen = true; sel = NEG_SENTINEL; }
    }
    denom = fmaxf(denom, 1e-12f);
    out[(size_t)row * EE + lane] = chosen ? (score / denom) : 0.0f;
    out[(size_t)nrows * EE + (size_t)row * EE + lane] = chosen ? 1.0f : 0.0f;
  }
}

// ---------------------------------------------------------------------------
extern "C" void kernel_launch(void* const* d_in, const int* in_sizes, int n_in,
                              void* d_out, int out_size, void* d_ws,
                              size_t ws_size, hipStream_t stream) {
  const float* hidden = (const float*)d_in[0];
  const float* gate_w = (const float*)d_in[1];
  const float* bias = (const float*)d_in[2];
  float* out = (float*)d_out;
  char* ws = (char*)d_ws;

  const int nrows = in_sizes[0] / DD;  // 16384

  // ws: bglob @0 (1MB) | part @2MB (16MB) | part2 @20MB (16MB) | tail ctr
  char* bglob = ws;
  float* part = (float*)(ws + (size_t)2 * 1024 * 1024);
  float* part2 = (float*)(ws + (size_t)20 * 1024 * 1024);
  size_t tail = (ws_size - 65536) & ~(size_t)255;
  int* counter = (int*)(ws + tail);
  int* list = counter + 1;

  hipMemsetAsync(counter, 0, sizeof(int), stream);
  presplit_b<<<dim3(128), dim3(256), 0, stream>>>(gate_w, bglob);
  gemm_mfma<<<dim3(nrows / 64, 4), dim3(256), 0, stream>>>(hidden, bglob, part,
                                                           nrows);
  topk_kernel<<<dim3(nrows / 4), dim3(256), 0, stream>>>(part, bias, out,
                                                         nrows, 4, counter,
                                                         list);
  fixup_partial<<<dim3(2048), dim3(256), 0, stream>>>(hidden, gate_w, counter,
                                                      list, part2);
  fixup_apply<<<dim3(512), dim3(256), 0, stream>>>(part2, bias, counter, list,
                                                   out, nrows);
}

// Round 14
// 111.664 us; speedup vs baseline: 1.2302x; 1.2302x over previous
//
#include <hip/hip_runtime.h>
#include <math.h>

#define DD 4096
#define EE 64
#define TAU 1e-4f
#define NEG_SENTINEL -1.0e30f
#define MAXFIX 4096

typedef __attribute__((ext_vector_type(8))) short short8v;
typedef __attribute__((ext_vector_type(4))) float f32x4;

union BF8 { uint4 u; short8v s; };

__device__ __forceinline__ unsigned asu(float f) {
  union { float f; unsigned u; } v; v.f = f; return v.u;
}
__device__ __forceinline__ float asf(unsigned u) {
  union { unsigned u; float f; } v; v.u = u; return v.f;
}
__device__ __forceinline__ unsigned rne_hi(float x) {  // bf16 bits<<16
  unsigned u = asu(x);
  return (u + 0x7fffu + ((u >> 16) & 1u)) & 0xffff0000u;
}
// Split 8 f32 into hi/lo bf16 (RNE both): x = hi + lo + O(2^-17 |x|).
__device__ __forceinline__ void split8(const float x[8], uint4& hi, uint4& lo) {
  unsigned h[8], l[8];
#pragma unroll
  for (int j = 0; j < 8; j++) {
    h[j] = rne_hi(x[j]);
    l[j] = rne_hi(x[j] - asf(h[j]));
  }
  hi = make_uint4((h[0] >> 16) | h[1], (h[2] >> 16) | h[3],
                  (h[4] >> 16) | h[5], (h[6] >> 16) | h[7]);
  lo = make_uint4((l[0] >> 16) | l[1], (l[2] >> 16) | l[3],
                  (l[4] >> 16) | l[5], (l[6] >> 16) | l[7]);
}
// global -> LDS direct copy, 16B/lane; LDS dest wave-uniform (HW adds l*16).
__device__ __forceinline__ void gload16(const void* g, void* l) {
  __builtin_amdgcn_global_load_lds(
      (const __attribute__((address_space(1))) uint32_t*)(uintptr_t)g,
      (__attribute__((address_space(3))) uint32_t*)(uint32_t)(uintptr_t)l, 16,
      0, 0);
}

// ---------------------------------------------------------------------------
// Kernel 0: pre-split gate_w into bf16 hi/lo in the gemm's exact STAGED
// layout: bglob[slice(512k)][step(32k)][hi|lo][e][slot16B]; source k-octet o
// of expert e lands at slot (o&3) ^ ((e>>1)&3) (read-side swizzle baked in;
// gemm stages each 8KB step verbatim per rule 21).
// ---------------------------------------------------------------------------
__global__ __launch_bounds__(256) void presplit_b(const float* __restrict__ gw,
                                                  char* __restrict__ bglob) {
  const int t = blockIdx.x * 256 + threadIdx.x;  // 64 e x 512 octets
  const int e = t >> 9;
  const int o = t & 511;
  const int slice = o >> 6;   // 64 octets per 512-k slice
  const int ow = o & 63;
  const int step = ow >> 2;   // 4 octets per 32-k step
  const int oslot = ow & 3;
  const float* src = gw + e * DD + o * 8;
  float4 v0 = *(const float4*)src;
  float4 v1 = *(const float4*)(src + 4);
  float x[8] = {v0.x, v0.y, v0.z, v0.w, v1.x, v1.y, v1.z, v1.w};
  uint4 hi, lo;
  split8(x, hi, lo);
  char* dst = bglob + (size_t)slice * 131072 + step * 8192 + e * 64 +
              ((oslot ^ ((e >> 1) & 3)) << 4);
  *(uint4*)dst = hi;
  *(uint4*)(dst + 4096) = lo;
}

// ---------------------------------------------------------------------------
// Kernel 1 (R14): R12-proven pipeline, B-restage share cut 4x.
// Block = 256 rows x 64 e; 4 waves; wave = 64 rows (mt=4) x 64 e (nt=4),
// acc 64 VGPR/lane. ksplit=8 -> grid (64,8)=512 = 2 blocks/CU.
// Per 32-k step per block: A 32KB (f32, source-swizzled gload_lds) + B 8KB
// (pre-split bf16, staged verbatim). LDS ring 2 x {A 32K, B 8K} = 80KB.
// Per wave per step: 8 A-gloads + 2 B-gloads; 16 ds_read_b128; 4 split8;
// 48 MFMA. stage(t+1) -> compute(t) -> __syncthreads (R12 order; R13's
// counted-vmcnt ring regressed and is reverted).
// ---------------------------------------------------------------------------
__global__ __launch_bounds__(256, 2) void gemm_mfma(
    const float* __restrict__ hidden, const char* __restrict__ bglob,
    float* __restrict__ part, int nrows) {
  __shared__ __align__(16) char smem[81920];  // 2 bufs x [A 32K | B 8K]

  const int lane = threadIdx.x & 63;
  const int wv = threadIdx.x >> 6;
  const int fr = lane & 15;
  const int fg = lane >> 4;  // 0..3
  const int m0 = blockIdx.x * 256;
  const int slice = blockIdx.y;  // ksplit = 8, kslice = 512
  const int k0 = slice * 512;

  // A sources: wave wv owns rows m0+64wv..+63; instr i covers rows 8i..8i+7.
  // lane l -> rloc = 8i+(l>>3), source slot (l&7)^(rloc&7) (phys slot l&7).
  const float* srcA[8];
#pragma unroll
  for (int i = 0; i < 8; i++) {
    const int rloc = 8 * i + (lane >> 3);
    const int s = (lane & 7) ^ (rloc & 7);
    srcA[i] = hidden + (size_t)(m0 + 64 * wv + rloc) * DD + k0 + s * 4;
  }
  const char* srcB = bglob + (size_t)slice * 131072 + wv * 2048 + lane * 16;

  auto stage = [&](int t) {
    const int buf = t & 1;
    char* ad = smem + buf * 40960 + wv * 8192;
    char* bd = smem + buf * 40960 + 32768 + wv * 2048;
#pragma unroll
    for (int i = 0; i < 8; i++) gload16(srcA[i] + t * 32, ad + i * 1024);
#pragma unroll
    for (int i = 0; i < 2; i++)
      gload16(srcB + t * 8192 + i * 1024, bd + i * 1024);
  };

  f32x4 zero4 = {0.f, 0.f, 0.f, 0.f};
  f32x4 acc[4][4];
#pragma unroll
  for (int mt = 0; mt < 4; mt++)
#pragma unroll
    for (int nt = 0; nt < 4; nt++) acc[mt][nt] = zero4;

  const int bslot = (fg ^ ((fr >> 1) & 3)) << 4;

  stage(0);
  __syncthreads();

  for (int t = 0; t < 16; t++) {
    if (t + 1 < 16) stage(t + 1);
    const char* Ab = smem + (t & 1) * 40960 + wv * 8192;
    const char* Bb = smem + (t & 1) * 40960 + 32768;
    // B frags once per step
    BF8 bh[4], bl[4];
#pragma unroll
    for (int nt = 0; nt < 4; nt++) {
      const int boff = (nt * 16 + fr) * 64 + bslot;
      bh[nt].u = *(const uint4*)(Bb + boff);
      bl[nt].u = *(const uint4*)(Bb + 4096 + boff);
    }
#pragma unroll
    for (int mt = 0; mt < 4; mt++) {
      const int arow = (mt * 16 + fr) * 128;
      float4 a0 = *(const float4*)(Ab + arow + (((2 * fg + 0) ^ (fr & 7)) << 4));
      float4 a1 = *(const float4*)(Ab + arow + (((2 * fg + 1) ^ (fr & 7)) << 4));
      float xa[8] = {a0.x, a0.y, a0.z, a0.w, a1.x, a1.y, a1.z, a1.w};
      BF8 ah, al;
      split8(xa, ah.u, al.u);
      // per-acc order hh -> hl -> lh (deterministic)
#pragma unroll
      for (int nt = 0; nt < 4; nt++)
        acc[mt][nt] = __builtin_amdgcn_mfma_f32_16x16x32_bf16(
            ah.s, bh[nt].s, acc[mt][nt], 0, 0, 0);
#pragma unroll
      for (int nt = 0; nt < 4; nt++)
        acc[mt][nt] = __builtin_amdgcn_mfma_f32_16x16x32_bf16(
            ah.s, bl[nt].s, acc[mt][nt], 0, 0, 0);
#pragma unroll
      for (int nt = 0; nt < 4; nt++)
        acc[mt][nt] = __builtin_amdgcn_mfma_f32_16x16x32_bf16(
            al.s, bh[nt].s, acc[mt][nt], 0, 0, 0);
    }
    __syncthreads();
  }

  // partial logits part[slice][row][e]; C/D row=fg*4+j, col=fr
  float* dst = part + (size_t)slice * nrows * EE;
#pragma unroll
  for (int mt = 0; mt < 4; mt++)
#pragma unroll
    for (int j = 0; j < 4; j++) {
      const int r = m0 + 64 * wv + mt * 16 + fg * 4 + j;
#pragma unroll
      for (int nt = 0; nt < 4; nt++)
        dst[(size_t)r * EE + nt * 16 + fr] = acc[mt][nt][j];
    }
}

// ---------------------------------------------------------------------------
// Kernel 2: reduce partials, sqrt(softplus), top-8 (lax.top_k tie-break),
// renormalize, scatter. Flags rows with margin < TAU for exact recompute.
// ---------------------------------------------------------------------------
__global__ __launch_bounds__(256) void topk_kernel(
    const float* __restrict__ part, const float* __restrict__ bias,
    float* __restrict__ out, int nrows, int ksplit, int* __restrict__ counter,
    int* __restrict__ list) {
  const int lane = threadIdx.x & 63;
  const int row = blockIdx.x * 4 + (threadIdx.x >> 6);

  float logit = 0.0f;
  for (int s = 0; s < ksplit; s++)
    logit += part[(size_t)s * nrows * EE + (size_t)row * EE + lane];

  float sp = (logit > 0.0f) ? (logit + log1pf(expf(-logit)))
                            : log1pf(expf(logit));
  float score = sqrtf(sp);
  float sel = score + bias[lane];

  float denom = 0.0f, v8 = 0.0f;
  bool chosen = false;
#pragma unroll
  for (int t = 0; t < 8; t++) {
    float v = sel;
    int idx = lane;
#pragma unroll
    for (int m = 1; m < 64; m <<= 1) {
      float ov = __shfl_xor(v, m, 64);
      int oi = __shfl_xor(idx, m, 64);
      if (ov > v || (ov == v && oi < idx)) { v = ov; idx = oi; }
    }
    float wscore = __shfl(score, idx, 64);
    denom += wscore;
    v8 = v;
    if (lane == idx) { chosen = true; sel = NEG_SENTINEL; }
  }
  float v9 = sel;
#pragma unroll
  for (int m = 1; m < 64; m <<= 1) v9 = fmaxf(v9, __shfl_xor(v9, m, 64));
  if (lane == 0 && (v8 - v9) < TAU) {
    int ix = atomicAdd(counter, 1);
    if (ix < MAXFIX) list[ix] = row;
  }

  denom = fmaxf(denom, 1e-12f);
  out[(size_t)row * EE + lane] = chosen ? (score / denom) : 0.0f;
  out[(size_t)nrows * EE + (size_t)row * EE + lane] = chosen ? 1.0f : 0.0f;
}

// ---------------------------------------------------------------------------
// Kernel 3a: exact-f32 partial dots for flagged rows, k-split 16 ways.
// ---------------------------------------------------------------------------
__global__ __launch_bounds__(256) void fixup_partial(
    const float* __restrict__ hidden, const float* __restrict__ gate_w,
    const int* __restrict__ counter, const int* __restrict__ list,
    float* __restrict__ part2) {
  __shared__ float red[EE][4];
  int cnt = *counter;
  if (cnt > MAXFIX) cnt = MAXFIX;
  const int total = cnt * 16;
  const int e = threadIdx.x & 63;
  const int q = threadIdx.x >> 6;
  for (int w = blockIdx.x; w < total; w += gridDim.x) {
    const int i = w >> 4;
    const int c = w & 15;
    const int row = list[i];
    const int kb = c * 256 + q * 64;
    const float* hp = hidden + (size_t)row * DD + kb;
    const float* wp = gate_w + (size_t)e * DD + kb;
    float s = 0.f;
#pragma unroll
    for (int k = 0; k < 64; k += 4) {
      float4 aa = *(const float4*)(hp + k);
      float4 bb = *(const float4*)(wp + k);
      s = fmaf(aa.w, bb.w, fmaf(aa.z, bb.z, fmaf(aa.y, bb.y, fmaf(aa.x, bb.x, s))));
    }
    red[e][q] = s;
    __syncthreads();
    if (threadIdx.x < EE)
      part2[(size_t)i * 1024 + threadIdx.x * 16 + c] =
          (red[threadIdx.x][0] + red[threadIdx.x][1]) +
          (red[threadIdx.x][2] + red[threadIdx.x][3]);
    __syncthreads();
  }
}

// ---------------------------------------------------------------------------
// Kernel 3b: sum the 16 chunks in fixed order, redo top-8 exactly, rewrite.
// ---------------------------------------------------------------------------
__global__ __launch_bounds__(256) void fixup_apply(
    const float* __restrict__ part2, const float* __restrict__ bias,
    const int* __restrict__ counter, const int* __restrict__ list,
    float* __restrict__ out, int nrows) {
  int cnt = *counter;
  if (cnt > MAXFIX) cnt = MAXFIX;
  const int lane = threadIdx.x & 63;
  const int wv = threadIdx.x >> 6;
  for (int i0 = blockIdx.x * 4; i0 < cnt; i0 += gridDim.x * 4) {
    const int i = i0 + wv;
    if (i >= cnt) continue;
    const int row = list[i];
    const float* pp = part2 + (size_t)i * 1024 + lane * 16;
    float logit = 0.f;
#pragma unroll
    for (int c = 0; c < 16; c++) logit += pp[c];
    float sp = (logit > 0.0f) ? (logit + log1pf(expf(-logit)))
                              : log1pf(expf(logit));
    float score = sqrtf(sp);
    float sel = score + bias[lane];
    float denom = 0.0f;
    bool chosen = false;
#pragma unroll
    for (int k = 0; k < 8; k++) {
      float v = sel;
      int idx = lane;
#pragma unroll
      for (int m = 1; m < 64; m <<= 1) {
        float ov = __shfl_xor(v, m, 64);
        int oi = __shfl_xor(idx, m, 64);
        if (ov > v || (ov == v && oi < idx)) { v = ov; idx = oi; }
      }
      float wscore = __shfl(score, idx, 64);
      denom += wscore;
      if (lane == idx) { chosen = true; sel = NEG_SENTINEL; }
    }
    denom = fmaxf(denom, 1e-12f);
    out[(size_t)row * EE + lane] = chosen ? (score / denom) : 0.0f;
    out[(size_t)nrows * EE + (size_t)row * EE + lane] = chosen ? 1.0f : 0.0f;
  }
}

// ---------------------------------------------------------------------------
extern "C" void kernel_launch(void* const* d_in, const int* in_sizes, int n_in,
                              void* d_out, int out_size, void* d_ws,
                              size_t ws_size, hipStream_t stream) {
  const float* hidden = (const float*)d_in[0];
  const float* gate_w = (const float*)d_in[1];
  const float* bias = (const float*)d_in[2];
  float* out = (float*)d_out;
  char* ws = (char*)d_ws;

  const int nrows = in_sizes[0] / DD;  // 16384

  // ws: bglob @0 (1MB) | part @2MB (32MB) | part2 @36MB (16MB) | tail ctr
  char* bglob = ws;
  float* part = (float*)(ws + (size_t)2 * 1024 * 1024);
  float* part2 = (float*)(ws + (size_t)36 * 1024 * 1024);
  size_t tail = (ws_size - 65536) & ~(size_t)255;
  int* counter = (int*)(ws + tail);
  int* list = counter + 1;

  hipMemsetAsync(counter, 0, sizeof(int), stream);
  presplit_b<<<dim3(128), dim3(256), 0, stream>>>(gate_w, bglob);
  gemm_mfma<<<dim3(nrows / 256, 8), dim3(256), 0, stream>>>(hidden, bglob,
                                                            part, nrows);
  topk_kernel<<<dim3(nrows / 4), dim3(256), 0, stream>>>(part, bias, out,
                                                         nrows, 8, counter,
                                                         list);
  fixup_partial<<<dim3(2048), dim3(256), 0, stream>>>(hidden, gate_w, counter,
                                                      list, part2);
  fixup_apply<<<dim3(512), dim3(256), 0, stream>>>(part2, bias, counter, list,
                                                   out, nrows);
}